// Round 9
// baseline (291.425 us; speedup 1.0000x reference)
//
#include <hip/hip_runtime.h>
#include <math.h>

// GAT model: N=50000, E=500000 (+N self loops), D=128, layer1 heads=4.
// Structure: CSR build; k_l1 (rank-1 layer 1); per layer:
//   k_aggh  (edge-softmax aggregate over h, wave/node, writes A-panel in MFMA
//            fragment-major bf16 hi/lo layout)
//   k_gemm  (MFMA bf16x3, NO LDS: A and B fragment-major coalesced loads,
//            fused bias/relu/alpha epilogue).
//
// Fragment layouts (16x16x32 bf16 MFMA, verified orientation from R4):
//   B frag for (ks,nn): lane=(kgrp<<4)|lrow reads k=ks*32+kgrp*8..+8, c=nn*16+lrow
//     wfrag[((ks*8+nn)*64 + lane)*8 + j]  (ushort), j=k&7
//   A frag for (tile,ks): lane reads row=tile*16+lrow, k=ks*32+kgrp*8..+8
//     afrag[((tile*4+ks)*64 + lane)*8 + j]

#define LEAKY(e) ((e) > 0.f ? (e) : 0.2f * (e))
#define SCAN_BLK 1024

typedef __attribute__((ext_vector_type(8))) short bf16x8;
typedef __attribute__((ext_vector_type(4))) float f32x4;

__device__ inline ushort f32_to_bf16_rne(float f) {
    unsigned u = __float_as_uint(f);
    unsigned r = (u + 0x7FFFu + ((u >> 16) & 1u)) >> 16;
    return (ushort)r;
}
__device__ inline float bf16_to_f32(ushort h) { return __uint_as_float((unsigned)h << 16); }
__device__ inline unsigned pack2(float a, float b) {
    return (unsigned)f32_to_bf16_rne(a) | ((unsigned)f32_to_bf16_rne(b) << 16);
}

// ---------------- CSR construction ----------------

__global__ void k_hist(const int* __restrict__ ei, int E, int N, int* __restrict__ deg) {
    int e = blockIdx.x * blockDim.x + threadIdx.x;
    int Et = E + N;
    if (e >= Et) return;
    int dst = (e < E) ? ei[2 * e + 1] : (e - E);
    atomicAdd(&deg[dst], 1);
}

__global__ __launch_bounds__(SCAN_BLK) void k_scan1(const int* __restrict__ deg,
                                                    int* __restrict__ tmp,
                                                    int* __restrict__ blocksum, int n) {
    __shared__ int buf[SCAN_BLK];
    int tid = threadIdx.x;
    int gid = blockIdx.x * SCAN_BLK + tid;
    int v = (gid < n) ? deg[gid] : 0;
    buf[tid] = v;
    __syncthreads();
#pragma unroll
    for (int off = 1; off < SCAN_BLK; off <<= 1) {
        int t = (tid >= off) ? buf[tid - off] : 0;
        __syncthreads();
        buf[tid] += t;
        __syncthreads();
    }
    if (gid < n) tmp[gid] = buf[tid] - v;
    if (tid == SCAN_BLK - 1) blocksum[blockIdx.x] = buf[tid];
}

__global__ __launch_bounds__(256) void k_scan2(const int* __restrict__ blocksum,
                                               int* __restrict__ blockoff, int nb,
                                               int* __restrict__ row_ptr, int n) {
    __shared__ int buf[256];
    int tid = threadIdx.x;
    int v = (tid < nb) ? blocksum[tid] : 0;
    buf[tid] = v;
    __syncthreads();
#pragma unroll
    for (int off = 1; off < 256; off <<= 1) {
        int t = (tid >= off) ? buf[tid - off] : 0;
        __syncthreads();
        buf[tid] += t;
        __syncthreads();
    }
    if (tid < nb) blockoff[tid] = buf[tid] - v;
    if (tid == 255) row_ptr[n] = buf[tid];
}

__global__ void k_scan3(const int* __restrict__ tmp, const int* __restrict__ blockoff,
                        int* __restrict__ row_ptr, int* __restrict__ cursor, int n) {
    int gid = blockIdx.x * blockDim.x + threadIdx.x;
    if (gid >= n) return;
    int v = tmp[gid] + blockoff[gid / SCAN_BLK];
    row_ptr[gid] = v;
    cursor[gid] = v;
}

__global__ void k_scatter(const int* __restrict__ ei, int E, int N,
                          int* __restrict__ cursor, int* __restrict__ csr_src) {
    int e = blockIdx.x * blockDim.x + threadIdx.x;
    int Et = E + N;
    if (e >= Et) return;
    int src, dst;
    if (e < E) { src = ei[2 * e]; dst = ei[2 * e + 1]; }
    else { src = dst = e - E; }
    int pos = atomicAdd(&cursor[dst], 1);
    csr_src[pos] = src;
}

// ---------------- Weight prep: fragment-major bf16 hi/lo ----------------

__global__ void k_wsplit3(const float* __restrict__ W0, const float* __restrict__ W1,
                          const float* __restrict__ W2,
                          ushort* __restrict__ hi0, ushort* __restrict__ lo0,
                          ushort* __restrict__ hi1, ushort* __restrict__ lo1,
                          ushort* __restrict__ hi2, ushort* __restrict__ lo2) {
    int l = blockIdx.x >> 6;
    int idx = (blockIdx.x & 63) * 256 + threadIdx.x;   // 0..16383
    const float* W = (l == 0) ? W0 : (l == 1) ? W1 : W2;
    ushort* ph = (l == 0) ? hi0 : (l == 1) ? hi1 : hi2;
    ushort* pl = (l == 0) ? lo0 : (l == 1) ? lo1 : lo2;
    int k = idx >> 7, c = idx & 127;
    float w = W[idx];
    ushort hi = f32_to_bf16_rne(w);
    ushort lo = f32_to_bf16_rne(w - bf16_to_f32(hi));
    int ks = k >> 5, kgrp = (k >> 3) & 3, j = k & 7;
    int nn = c >> 4, lrow = c & 15;
    int off = (((ks * 8 + nn) * 64) + kgrp * 16 + lrow) * 8 + j;
    ph[off] = hi;
    pl[off] = lo;
}

__global__ void k_wvec3(const float* __restrict__ W0, const float* __restrict__ W1,
                        const float* __restrict__ W2,
                        const float* __restrict__ as0, const float* __restrict__ as1,
                        const float* __restrict__ as2,
                        const float* __restrict__ ad0, const float* __restrict__ ad1,
                        const float* __restrict__ ad2,
                        float* __restrict__ was0, float* __restrict__ was1,
                        float* __restrict__ was2,
                        float* __restrict__ wad0, float* __restrict__ wad1,
                        float* __restrict__ wad2) {
    int l = blockIdx.x;
    const float* W  = (l == 0) ? W0 : (l == 1) ? W1 : W2;
    const float* av = (l == 0) ? as0 : (l == 1) ? as1 : as2;
    const float* dv = (l == 0) ? ad0 : (l == 1) ? ad1 : ad2;
    float* ws = (l == 0) ? was0 : (l == 1) ? was1 : was2;
    float* wd = (l == 0) ? wad0 : (l == 1) ? wad1 : wad2;
    int k = threadIdx.x;  // 128
    float s = 0.f, d = 0.f;
    for (int c = 0; c < 128; c++) {
        float w = W[k * 128 + c];
        s += w * av[c];
        d += w * dv[c];
    }
    ws[k] = s; wd[k] = d;
}

// ---------------- Layer-1 rank-1 constants ----------------
// consts layout: u[128]@0, v[128]@128, P[4]@256, Q[4]@260, R[4]@264, S[4]@268

__global__ void k_emb(const float* __restrict__ W_emb, const float* __restrict__ b_emb,
                      const float* __restrict__ W1, const float* __restrict__ as1,
                      const float* __restrict__ ad1, float* __restrict__ consts) {
    __shared__ float su[128], sv[128];
    int f = threadIdx.x;  // 128 threads
    float u = 0.f, v = 0.f;
    for (int k = 0; k < 128; k++) {
        u += W_emb[k] * W1[k * 128 + f];
        v += b_emb[k] * W1[k * 128 + f];
    }
    su[f] = u; sv[f] = v;
    consts[f] = u; consts[128 + f] = v;
    __syncthreads();
    if (f < 4) {
        float P = 0.f, Q = 0.f, R = 0.f, S = 0.f;
        for (int j = 0; j < 32; j++) {
            float uu = su[f * 32 + j], vv = sv[f * 32 + j];
            float a = as1[f * 32 + j], d = ad1[f * 32 + j];
            P += uu * a; Q += vv * a; R += uu * d; S += vv * d;
        }
        consts[256 + f] = P; consts[260 + f] = Q; consts[264 + f] = R; consts[268 + f] = S;
    }
}

// ---------------- Layer 1 fused, quad-per-node (lane q = head q) ----------------
__global__ __launch_bounds__(256) void k_l1(const float* __restrict__ x,
        const int* __restrict__ row_ptr, const int* __restrict__ csr_src,
        const float* __restrict__ consts, const float* __restrict__ b1,
        const float* __restrict__ was2, const float* __restrict__ wad2,
        float* __restrict__ hout, float* __restrict__ a_s, float* __restrict__ a_d, int n) {
    __shared__ float sm[64][4], smw[64][4];
    int tid = threadIdx.x;
    int nl = tid >> 2, q = tid & 3;
    int node = blockIdx.x * 64 + nl;
    bool valid = node < n;
    float P = consts[256 + q], Q = consts[260 + q];
    float R = consts[264 + q], Sc = consts[268 + q];
    float den = 0.f, S = 0.f;
    if (valid) {
        float xd = x[node];
        float c0 = xd * R + Sc + Q;      // e = leaky(xs*P + c0)
        int s0 = row_ptr[node], s1 = row_ptr[node + 1];
        for (int i = s0; i < s1; i++) {
            float xs = x[csr_src[i]];
            float e = xs * P + c0;
            e = LEAKY(e);
            float w = __expf(e);
            den += w;
            S += w * xs;
        }
    }
    float inv = 1.f / (den + 1e-16f);
    sm[nl][q] = S * inv;
    smw[nl][q] = den * inv;
    __syncthreads();
    float Sn = sm[nl][q], Swn = smw[nl][q];
    float ps = 0.f, pd = 0.f;
    if (valid) {
#pragma unroll
        for (int j = 0; j < 8; j++) {
            int f = q * 32 + j * 4;
            float4 u = *(const float4*)(consts + f);
            float4 v = *(const float4*)(consts + 128 + f);
            float4 b = *(const float4*)(b1 + f);
            float4 ws = *(const float4*)(was2 + f);
            float4 wd = *(const float4*)(wad2 + f);
            float4 val;
            val.x = fmaxf(Sn * u.x + Swn * v.x + b.x, 0.f);
            val.y = fmaxf(Sn * u.y + Swn * v.y + b.y, 0.f);
            val.z = fmaxf(Sn * u.z + Swn * v.z + b.z, 0.f);
            val.w = fmaxf(Sn * u.w + Swn * v.w + b.w, 0.f);
            *(float4*)(hout + (size_t)node * 128 + f) = val;
            ps += val.x * ws.x + val.y * ws.y + val.z * ws.z + val.w * ws.w;
            pd += val.x * wd.x + val.y * wd.y + val.z * wd.z + val.w * wd.w;
        }
    }
    ps += __shfl_xor(ps, 1, 64); ps += __shfl_xor(ps, 2, 64);
    pd += __shfl_xor(pd, 1, 64); pd += __shfl_xor(pd, 2, 64);
    if (q == 0 && valid) { a_s[node] = ps; a_d[node] = pd; }
}

// ---------------- Aggregation over h -> A panel in fragment-major hi/lo ----------------
__global__ __launch_bounds__(256) void k_aggh(const float* __restrict__ h,
        const float* __restrict__ as, const float* __restrict__ ad,
        const int* __restrict__ row_ptr, const int* __restrict__ csr_src,
        ushort* __restrict__ afrag_hi, ushort* __restrict__ afrag_lo, int n) {
    __shared__ int2 s_sw[4][64];
    int w = threadIdx.x >> 6, lane = threadIdx.x & 63;
    int node = blockIdx.x * 4 + w;
    if (node >= n) return;
    int s0 = row_ptr[node], s1 = row_ptr[node + 1];
    int deg = s1 - s0;
    float adval = ad[node];
    const char* hbase = (const char*)h;
    size_t tbase = (size_t)(node >> 4) * 4 * 64 * 8;   // tile base (ushort units)
    int lrow16 = node & 15;

    if (deg <= 64) {
        int boff = 0;
        float e = -INFINITY;
        if (lane < deg) {
            int src = csr_src[s0 + lane];
            boff = src << 9;                  // src * 512 bytes
            e = LEAKY(as[src] + adval);
        }
        float m = e;
#pragma unroll
        for (int off = 32; off > 0; off >>= 1) m = fmaxf(m, __shfl_xor(m, off, 64));
        float wt = (lane < deg) ? __expf(e - m) : 0.f;
        float den = wt;
#pragma unroll
        for (int off = 32; off > 0; off >>= 1) den += __shfl_xor(den, off, 64);
        s_sw[w][lane] = make_int2(boff, __float_as_int(wt));   // zero-padded beyond deg
        __builtin_amdgcn_wave_barrier();

        int half = lane >> 5;          // which edge of the pair
        int q16 = (lane & 31) * 16;    // byte offset of this lane's feature quad
        float4 acc = make_float4(0.f, 0.f, 0.f, 0.f);
        int degp = (deg + 7) & ~7;
        for (int j = 0; j < degp; j += 8) {
#pragma unroll
            for (int t = 0; t < 4; t++) {
                int2 p = s_sw[w][j + 2 * t + half];
                float4 v = *(const float4*)(hbase + p.x + q16);
                float wt2 = __int_as_float(p.y);
                acc.x += wt2 * v.x; acc.y += wt2 * v.y;
                acc.z += wt2 * v.z; acc.w += wt2 * v.w;
            }
        }
        acc.x += __shfl_xor(acc.x, 32, 64);
        acc.y += __shfl_xor(acc.y, 32, 64);
        acc.z += __shfl_xor(acc.z, 32, 64);
        acc.w += __shfl_xor(acc.w, 32, 64);
        float inv = 1.f / (den + 1e-16f);
        if (lane < 32) {
            // lane l holds features f0=4l..4l+3 (= k indices)
            float o0 = acc.x * inv, o1 = acc.y * inv;
            float o2 = acc.z * inv, o3 = acc.w * inv;
            ushort h0 = f32_to_bf16_rne(o0), h1 = f32_to_bf16_rne(o1);
            ushort h2 = f32_to_bf16_rne(o2), h3 = f32_to_bf16_rne(o3);
            unsigned hi01 = (unsigned)h0 | ((unsigned)h1 << 16);
            unsigned hi23 = (unsigned)h2 | ((unsigned)h3 << 16);
            unsigned lo01 = pack2(o0 - bf16_to_f32(h0), o1 - bf16_to_f32(h1));
            unsigned lo23 = pack2(o2 - bf16_to_f32(h2), o3 - bf16_to_f32(h3));
            int ks = lane >> 3;                 // k=4l: ks = 4l/32
            int kgrp = (lane >> 1) & 3;         // (4l/8)&3
            int j0 = (lane & 1) * 4;            // 4l & 7
            size_t off = tbase + ((size_t)ks * 64 + kgrp * 16 + lrow16) * 8 + j0;
            *(uint2*)(afrag_hi + off) = make_uint2(hi01, hi23);
            *(uint2*)(afrag_lo + off) = make_uint2(lo01, lo23);
        }
    } else {
        // generic fallback (recompute per edge); lane holds features 2l, 2l+1
        int lane8 = lane * 8;
        float m = -INFINITY;
        for (int i = s0 + lane; i < s1; i += 64) {
            float e = LEAKY(as[csr_src[i]] + adval);
            m = fmaxf(m, e);
        }
#pragma unroll
        for (int off = 32; off > 0; off >>= 1) m = fmaxf(m, __shfl_xor(m, off, 64));
        float den = 0.f;
        float2 acc = make_float2(0.f, 0.f);
        for (int i = s0; i < s1; i++) {
            int src = csr_src[i];
            float e = LEAKY(as[src] + adval);
            float wt = __expf(e - m);
            den += wt;
            float2 v = *(const float2*)(hbase + ((size_t)src << 9) + lane8);
            acc.x += wt * v.x; acc.y += wt * v.y;
        }
        float inv = 1.f / (den + 1e-16f);
        float o0 = acc.x * inv, o1 = acc.y * inv;
        ushort h0 = f32_to_bf16_rne(o0), h1 = f32_to_bf16_rne(o1);
        int k = 2 * lane;
        int ks = k >> 5, kgrp = (k >> 3) & 3, j0 = k & 7;
        size_t off = tbase + ((size_t)ks * 64 + kgrp * 16 + lrow16) * 8 + j0;
        *(unsigned*)(afrag_hi + off) = (unsigned)h0 | ((unsigned)h1 << 16);
        *(unsigned*)(afrag_lo + off) = pack2(o0 - bf16_to_f32(h0), o1 - bf16_to_f32(h1));
    }
}

// ---------------- MFMA GEMM, no LDS: all operands fragment-major ----------------
// 256 threads = 4 waves; block = 64 rows; wave = 16 rows x 128 cols; K=128.
__global__ __launch_bounds__(256) void k_gemm(
        const ushort* __restrict__ afrag_hi, const ushort* __restrict__ afrag_lo,
        const ushort* __restrict__ wf_hi, const ushort* __restrict__ wf_lo,
        const float* __restrict__ bias, float* __restrict__ hout,
        const float* __restrict__ was_nx, const float* __restrict__ wad_nx,
        float* __restrict__ as_nx, float* __restrict__ ad_nx,
        int n, int do_relu) {
    int tid = threadIdx.x, wid = tid >> 6, lane = tid & 63;
    int lrow = lane & 15, kgrp = lane >> 4;
    int tile = blockIdx.x * 4 + wid;
    int row_base = tile * 16;

    f32x4 acc[8];
#pragma unroll
    for (int nn = 0; nn < 8; nn++) { acc[nn][0] = 0.f; acc[nn][1] = 0.f; acc[nn][2] = 0.f; acc[nn][3] = 0.f; }

#pragma unroll
    for (int ks = 0; ks < 4; ks++) {
        size_t aoff = ((size_t)(tile * 4 + ks) * 64 + lane) * 8;
        bf16x8 ah = *(const bf16x8*)(afrag_hi + aoff);
        bf16x8 al = *(const bf16x8*)(afrag_lo + aoff);
#pragma unroll
        for (int nn = 0; nn < 8; nn++) {
            size_t boff = ((size_t)(ks * 8 + nn) * 64 + lane) * 8;
            bf16x8 bh = *(const bf16x8*)(wf_hi + boff);
            bf16x8 bl = *(const bf16x8*)(wf_lo + boff);
            acc[nn] = __builtin_amdgcn_mfma_f32_16x16x32_bf16(ah, bh, acc[nn], 0, 0, 0);
            acc[nn] = __builtin_amdgcn_mfma_f32_16x16x32_bf16(ah, bl, acc[nn], 0, 0, 0);
            acc[nn] = __builtin_amdgcn_mfma_f32_16x16x32_bf16(al, bh, acc[nn], 0, 0, 0);
        }
    }

    float bv[8], wsv[8], wdv[8];
#pragma unroll
    for (int nn = 0; nn < 8; nn++) bv[nn] = bias[nn * 16 + lrow];
    if (was_nx) {
#pragma unroll
        for (int nn = 0; nn < 8; nn++) {
            wsv[nn] = was_nx[nn * 16 + lrow];
            wdv[nn] = wad_nx[nn * 16 + lrow];
        }
    }

#pragma unroll
    for (int i = 0; i < 4; i++) {
        int row = row_base + kgrp * 4 + i;
        if (row < n) {
            float ps = 0.f, pd = 0.f;
#pragma unroll
            for (int nn = 0; nn < 8; nn++) {
                float val = acc[nn][i] + bv[nn];
                if (do_relu) val = fmaxf(val, 0.f);
                hout[(size_t)row * 128 + nn * 16 + lrow] = val;
                if (was_nx) { ps += val * wsv[nn]; pd += val * wdv[nn]; }
            }
            if (was_nx) {
#pragma unroll
                for (int off = 1; off < 16; off <<= 1) {
                    ps += __shfl_xor(ps, off, 16);
                    pd += __shfl_xor(pd, off, 16);
                }
                if (lrow == 0) { as_nx[row] = ps; ad_nx[row] = pd; }
            }
        }
    }
}

// ---------------- launch ----------------

extern "C" void kernel_launch(void* const* d_in, const int* in_sizes, int n_in,
                              void* d_out, int out_size, void* d_ws, size_t ws_size,
                              hipStream_t stream) {
    const float* x     = (const float*)d_in[0];
    const int*   ei    = (const int*)d_in[1];
    const float* W_emb = (const float*)d_in[2];
    const float* b_emb = (const float*)d_in[3];
    const float* W1    = (const float*)d_in[4];
    const float* as1   = (const float*)d_in[5];
    const float* ad1   = (const float*)d_in[6];
    const float* b1    = (const float*)d_in[7];
    const float* Wl[3]  = {(const float*)d_in[8],  (const float*)d_in[12], (const float*)d_in[16]};
    const float* asl[3] = {(const float*)d_in[9],  (const float*)d_in[13], (const float*)d_in[17]};
    const float* adl[3] = {(const float*)d_in[10], (const float*)d_in[14], (const float*)d_in[18]};
    const float* bl[3]  = {(const float*)d_in[11], (const float*)d_in[15], (const float*)d_in[19]};
    float* out = (float*)d_out;

    int N = in_sizes[0];
    int E = in_sizes[1] / 2;
    int Et = E + N;
    int nb = (N + SCAN_BLK - 1) / SCAN_BLK;
    int ntile = (N + 15) / 16;
    int ngblk = (N + 63) / 64;            // k_gemm blocks (4 tiles each)

    char* ws = (char*)d_ws;
    size_t off = 0;
    auto alloc = [&](size_t bytes) { size_t p = off; off += (bytes + 255) & ~(size_t)255; return p; };
    int*   deg      = (int*)(ws + alloc((size_t)N * 4));
    int*   row_ptr  = (int*)(ws + alloc((size_t)(N + 1) * 4));
    int*   cursor   = (int*)(ws + alloc((size_t)N * 4));
    int*   csr_src  = (int*)(ws + alloc((size_t)Et * 4));
    int*   scantmp  = (int*)(ws + alloc((size_t)N * 4));
    int*   blocksum = (int*)(ws + alloc((size_t)nb * 4));
    int*   blockoff = (int*)(ws + alloc((size_t)nb * 4));
    float* consts   = (float*)(ws + alloc(272 * 4));
    float* a_s0     = (float*)(ws + alloc((size_t)N * 4));
    float* a_d0     = (float*)(ws + alloc((size_t)N * 4));
    float* a_s1     = (float*)(ws + alloc((size_t)N * 4));
    float* a_d1     = (float*)(ws + alloc((size_t)N * 4));
    float* hA       = (float*)(ws + alloc((size_t)N * 128 * 4));
    // A-frag planes: pad to gemm-grid tiles (4 per block) so tail reads are in-bounds
    size_t atiles = (size_t)ngblk * 4;
    ushort* afrag_hi = (ushort*)(ws + alloc(atiles * 4 * 64 * 8 * 2));
    ushort* afrag_lo = (ushort*)(ws + alloc(atiles * 4 * 64 * 8 * 2));
    ushort* wf_hi[3]; ushort* wf_lo[3];
    float* was[3]; float* wad[3];
    for (int l = 0; l < 3; l++) {
        wf_hi[l] = (ushort*)(ws + alloc(4 * 8 * 64 * 8 * 2));   // 32 KB
        wf_lo[l] = (ushort*)(ws + alloc(4 * 8 * 64 * 8 * 2));
        was[l]   = (float*)(ws + alloc(128 * 4));
        wad[l]   = (float*)(ws + alloc(128 * 4));
    }

    hipMemsetAsync(deg, 0, (size_t)N * 4, stream);
    k_hist<<<(Et + 255) / 256, 256, 0, stream>>>(ei, E, N, deg);
    k_scan1<<<nb, SCAN_BLK, 0, stream>>>(deg, scantmp, blocksum, N);
    k_scan2<<<1, 256, 0, stream>>>(blocksum, blockoff, nb, row_ptr, N);
    k_scan3<<<(N + 255) / 256, 256, 0, stream>>>(scantmp, blockoff, row_ptr, cursor, N);
    k_scatter<<<(Et + 255) / 256, 256, 0, stream>>>(ei, E, N, cursor, csr_src);

    k_wsplit3<<<192, 256, 0, stream>>>(Wl[0], Wl[1], Wl[2],
                                       wf_hi[0], wf_lo[0], wf_hi[1], wf_lo[1], wf_hi[2], wf_lo[2]);
    k_wvec3<<<3, 128, 0, stream>>>(Wl[0], Wl[1], Wl[2], asl[0], asl[1], asl[2],
                                   adl[0], adl[1], adl[2],
                                   was[0], was[1], was[2], wad[0], wad[1], wad[2]);
    k_emb<<<1, 128, 0, stream>>>(W_emb, b_emb, W1, as1, ad1, consts);

    k_l1<<<(N + 63) / 64, 256, 0, stream>>>(x, row_ptr, csr_src, consts, b1,
                                            was[0], wad[0], hA, a_s0, a_d0, N);

    float* as_cur = a_s0; float* ad_cur = a_d0;
    float* as_nxt = a_s1; float* ad_nxt = a_d1;
    for (int l = 0; l < 3; l++) {
        k_aggh<<<(N + 3) / 4, 256, 0, stream>>>(hA, as_cur, ad_cur, row_ptr, csr_src,
                                                afrag_hi, afrag_lo, N);
        if (l < 2) {
            k_gemm<<<ngblk, 256, 0, stream>>>(afrag_hi, afrag_lo, wf_hi[l], wf_lo[l], bl[l], hA,
                                              was[l + 1], wad[l + 1], as_nxt, ad_nxt, N, 1);
            float* t;
            t = as_cur; as_cur = as_nxt; as_nxt = t;
            t = ad_cur; ad_cur = ad_nxt; ad_nxt = t;
        } else {
            k_gemm<<<ngblk, 256, 0, stream>>>(afrag_hi, afrag_lo, wf_hi[l], wf_lo[l], bl[l], out,
                                              nullptr, nullptr, nullptr, nullptr, N, 0);
        }
    }
}

// Round 10
// 247.749 us; speedup vs baseline: 1.1763x; 1.1763x over previous
//
#include <hip/hip_runtime.h>
#include <math.h>

// GAT model: N=50000, E=500000 (+N self loops), D=128, layer1 heads=4.
// R8 structure (best measured) + padded-CSR (no scan) + merged prep:
//   k_scatterpad: csr_pad[dst][64] via atomicAdd, overflow list for deg>64
//   k_prep: weight bf16 hi/lo split + was/wad + layer-1 rank-1 constants
//   k_l1: rank-1 layer 1 (quad per node)
//   per layer: k_aggh (edge-softmax aggregate over h, wave/node -> bf16 hi/lo aggp)
//              k_gemm (MFMA bf16x3, B staged in LDS, fused epilogue)

#define LEAKY(e) ((e) > 0.f ? (e) : 0.2f * (e))

typedef __attribute__((ext_vector_type(8))) short bf16x8;
typedef __attribute__((ext_vector_type(4))) float f32x4;

__device__ inline ushort f32_to_bf16_rne(float f) {
    unsigned u = __float_as_uint(f);
    unsigned r = (u + 0x7FFFu + ((u >> 16) & 1u)) >> 16;
    return (ushort)r;
}
__device__ inline float bf16_to_f32(ushort h) { return __uint_as_float((unsigned)h << 16); }
__device__ inline unsigned pack2(float a, float b) {
    return (unsigned)f32_to_bf16_rne(a) | ((unsigned)f32_to_bf16_rne(b) << 16);
}

// ---------------- Padded CSR: one pass, no scan ----------------

__global__ void k_scatterpad(const int* __restrict__ ei, int E, int N,
                             int* __restrict__ deg, int* __restrict__ csr_pad,
                             int* __restrict__ ovf_cnt, int2* __restrict__ ovf,
                             int ovf_cap) {
    int e = blockIdx.x * blockDim.x + threadIdx.x;
    int Et = E + N;
    if (e >= Et) return;
    int src, dst;
    if (e < E) { int2 p = ((const int2*)ei)[e]; src = p.x; dst = p.y; }
    else { src = dst = e - E; }
    int pos = atomicAdd(&deg[dst], 1);
    if (pos < 64) {
        csr_pad[(dst << 6) + pos] = src;
    } else {
        int o = atomicAdd(ovf_cnt, 1);
        if (o < ovf_cap) ovf[o] = make_int2(dst, src);
    }
}

// ---------------- Merged prep: wsplit (blocks 0-191), wvec (192-194), emb (195) ----
// consts layout: u[128]@0, v[128]@128, P[4]@256, Q[4]@260, R[4]@264, S[4]@268

__global__ void k_prep(const float* __restrict__ Wa, const float* __restrict__ Wb,
                       const float* __restrict__ Wc,
                       const float* __restrict__ asa, const float* __restrict__ asb,
                       const float* __restrict__ asc,
                       const float* __restrict__ ada, const float* __restrict__ adb,
                       const float* __restrict__ adc,
                       const float* __restrict__ W_emb, const float* __restrict__ b_emb,
                       const float* __restrict__ W1g, const float* __restrict__ as1g,
                       const float* __restrict__ ad1g,
                       ushort* __restrict__ hi0, ushort* __restrict__ lo0,
                       ushort* __restrict__ hi1, ushort* __restrict__ lo1,
                       ushort* __restrict__ hi2, ushort* __restrict__ lo2,
                       float* __restrict__ was0, float* __restrict__ was1,
                       float* __restrict__ was2,
                       float* __restrict__ wad0, float* __restrict__ wad1,
                       float* __restrict__ wad2,
                       float* __restrict__ consts) {
    __shared__ float su[128], sv[128];
    int b = blockIdx.x, tid = threadIdx.x;
    if (b < 192) {
        int l = b >> 6;
        int idx = (b & 63) * 256 + tid;   // 0..16383
        const float* W = (l == 0) ? Wa : (l == 1) ? Wb : Wc;
        ushort* ph = (l == 0) ? hi0 : (l == 1) ? hi1 : hi2;
        ushort* pl = (l == 0) ? lo0 : (l == 1) ? lo1 : lo2;
        int k = idx >> 7, c = idx & 127;
        float w = W[idx];
        ushort hi = f32_to_bf16_rne(w);
        ushort lo = f32_to_bf16_rne(w - bf16_to_f32(hi));
        ph[c * 128 + k] = hi;     // transposed: [col][k]
        pl[c * 128 + k] = lo;
    } else if (b < 195) {
        if (tid >= 128) return;
        int l = b - 192;
        const float* W  = (l == 0) ? Wa : (l == 1) ? Wb : Wc;
        const float* av = (l == 0) ? asa : (l == 1) ? asb : asc;
        const float* dv = (l == 0) ? ada : (l == 1) ? adb : adc;
        float* ws = (l == 0) ? was0 : (l == 1) ? was1 : was2;
        float* wd = (l == 0) ? wad0 : (l == 1) ? wad1 : wad2;
        int k = tid;
        float s = 0.f, d = 0.f;
        for (int c = 0; c < 128; c++) {
            float w = W[k * 128 + c];
            s += w * av[c];
            d += w * dv[c];
        }
        ws[k] = s; wd[k] = d;
    } else {
        if (tid >= 128) return;
        int f = tid;
        float u = 0.f, v = 0.f;
        for (int k = 0; k < 128; k++) {
            u += W_emb[k] * W1g[k * 128 + f];
            v += b_emb[k] * W1g[k * 128 + f];
        }
        su[f] = u; sv[f] = v;
        consts[f] = u; consts[128 + f] = v;
        __syncthreads();
        if (f < 4) {
            float P = 0.f, Q = 0.f, R = 0.f, S = 0.f;
            for (int j = 0; j < 32; j++) {
                float uu = su[f * 32 + j], vv = sv[f * 32 + j];
                float a = as1g[f * 32 + j], d = ad1g[f * 32 + j];
                P += uu * a; Q += vv * a; R += uu * d; S += vv * d;
            }
            consts[256 + f] = P; consts[260 + f] = Q;
            consts[264 + f] = R; consts[268 + f] = S;
        }
    }
}

// ---------------- Layer 1 fused, quad-per-node (lane q = head q) ----------------
__global__ __launch_bounds__(256) void k_l1(const float* __restrict__ x,
        const int* __restrict__ deg, const int* __restrict__ csr_pad,
        const int* __restrict__ ovf_cnt, const int2* __restrict__ ovf,
        const float* __restrict__ consts, const float* __restrict__ b1,
        const float* __restrict__ was2, const float* __restrict__ wad2,
        float* __restrict__ hout, float* __restrict__ a_s, float* __restrict__ a_d, int n) {
    __shared__ float sm[64][4], smw[64][4];
    int tid = threadIdx.x;
    int nl = tid >> 2, q = tid & 3;
    int node = blockIdx.x * 64 + nl;
    bool valid = node < n;
    float P = consts[256 + q], Q = consts[260 + q];
    float R = consts[264 + q], Sc = consts[268 + q];
    float den = 0.f, S = 0.f;
    if (valid) {
        float xd = x[node];
        float c0 = xd * R + Sc + Q;      // e = leaky(xs*P + c0)
        int dg = deg[node];
        int dlim = min(dg, 64);
        for (int i = 0; i < dlim; i++) {
            float xs = x[csr_pad[(node << 6) + i]];
            float e = xs * P + c0;
            e = LEAKY(e);
            float w = __expf(e);
            den += w;
            S += w * xs;
        }
        if (dg > 64) {
            int no = *ovf_cnt;
            for (int i = 0; i < no; i++) {
                int2 p = ovf[i];
                if (p.x == node) {
                    float xs = x[p.y];
                    float e = xs * P + c0;
                    e = LEAKY(e);
                    float w = __expf(e);
                    den += w;
                    S += w * xs;
                }
            }
        }
    }
    float inv = 1.f / (den + 1e-16f);
    sm[nl][q] = S * inv;
    smw[nl][q] = den * inv;
    __syncthreads();
    float Sn = sm[nl][q], Swn = smw[nl][q];
    float ps = 0.f, pd = 0.f;
    if (valid) {
#pragma unroll
        for (int j = 0; j < 8; j++) {
            int f = q * 32 + j * 4;
            float4 u = *(const float4*)(consts + f);
            float4 v = *(const float4*)(consts + 128 + f);
            float4 b = *(const float4*)(b1 + f);
            float4 ws = *(const float4*)(was2 + f);
            float4 wd = *(const float4*)(wad2 + f);
            float4 val;
            val.x = fmaxf(Sn * u.x + Swn * v.x + b.x, 0.f);
            val.y = fmaxf(Sn * u.y + Swn * v.y + b.y, 0.f);
            val.z = fmaxf(Sn * u.z + Swn * v.z + b.z, 0.f);
            val.w = fmaxf(Sn * u.w + Swn * v.w + b.w, 0.f);
            *(float4*)(hout + (size_t)node * 128 + f) = val;
            ps += val.x * ws.x + val.y * ws.y + val.z * ws.z + val.w * ws.w;
            pd += val.x * wd.x + val.y * wd.y + val.z * wd.z + val.w * wd.w;
        }
    }
    ps += __shfl_xor(ps, 1, 64); ps += __shfl_xor(ps, 2, 64);
    pd += __shfl_xor(pd, 1, 64); pd += __shfl_xor(pd, 2, 64);
    if (q == 0 && valid) { a_s[node] = ps; a_d[node] = pd; }
}

// ---------------- Aggregation over h (f32), output packed bf16 hi/lo ----------------
// One wave per dst node. Fast path: float4 gather, two edges/iteration
// (lanes 0-31 -> edge j, lanes 32-63 -> edge j+1); LDS zero-padded, no tail.
__global__ __launch_bounds__(256) void k_aggh(const float* __restrict__ h,
        const float* __restrict__ as, const float* __restrict__ ad,
        const int* __restrict__ deg, const int* __restrict__ csr_pad,
        const int* __restrict__ ovf_cnt, const int2* __restrict__ ovf,
        unsigned* __restrict__ aggp, int n) {
    __shared__ int2 s_sw[4][64];
    int w = threadIdx.x >> 6, lane = threadIdx.x & 63;
    int node = blockIdx.x * 4 + w;
    if (node >= n) return;
    int dg = deg[node];
    float adval = ad[node];
    const char* hbase = (const char*)h;

    if (dg <= 64) {
        int boff = 0;
        float e = -INFINITY;
        if (lane < dg) {
            int src = csr_pad[(node << 6) + lane];
            boff = src << 9;                  // src * 512 bytes
            e = LEAKY(as[src] + adval);
        }
        float m = e;
#pragma unroll
        for (int off = 32; off > 0; off >>= 1) m = fmaxf(m, __shfl_xor(m, off, 64));
        float wt = (lane < dg) ? __expf(e - m) : 0.f;
        float den = wt;
#pragma unroll
        for (int off = 32; off > 0; off >>= 1) den += __shfl_xor(den, off, 64);
        s_sw[w][lane] = make_int2(boff, __float_as_int(wt));   // zero-padded beyond deg
        __builtin_amdgcn_wave_barrier();

        int half = lane >> 5;          // which edge of the pair
        int q16 = (lane & 31) * 16;    // byte offset of this lane's feature quad
        float4 acc = make_float4(0.f, 0.f, 0.f, 0.f);
        int degp = (dg + 7) & ~7;
        for (int j = 0; j < degp; j += 8) {
#pragma unroll
            for (int t = 0; t < 4; t++) {
                int2 p = s_sw[w][j + 2 * t + half];
                float4 v = *(const float4*)(hbase + p.x + q16);
                float wt2 = __int_as_float(p.y);
                acc.x += wt2 * v.x; acc.y += wt2 * v.y;
                acc.z += wt2 * v.z; acc.w += wt2 * v.w;
            }
        }
        acc.x += __shfl_xor(acc.x, 32, 64);
        acc.y += __shfl_xor(acc.y, 32, 64);
        acc.z += __shfl_xor(acc.z, 32, 64);
        acc.w += __shfl_xor(acc.w, 32, 64);
        float inv = 1.f / (den + 1e-16f);
        if (lane < 32) {
            float o0 = acc.x * inv, o1 = acc.y * inv;
            float o2 = acc.z * inv, o3 = acc.w * inv;
            ushort h0 = f32_to_bf16_rne(o0), h1 = f32_to_bf16_rne(o1);
            ushort h2 = f32_to_bf16_rne(o2), h3 = f32_to_bf16_rne(o3);
            uint4 pk;
            pk.x = (unsigned)h0 | ((unsigned)h1 << 16);
            pk.y = pack2(o0 - bf16_to_f32(h0), o1 - bf16_to_f32(h1));
            pk.z = (unsigned)h2 | ((unsigned)h3 << 16);
            pk.w = pack2(o2 - bf16_to_f32(h2), o3 - bf16_to_f32(h3));
            ((uint4*)aggp)[(size_t)node * 32 + lane] = pk;
        }
    } else {
        // deg > 64: 64 padded edges + overflow list scan (rare/never on this graph)
        int lane8 = lane * 8;
        int no = *ovf_cnt;
        int psrc = csr_pad[(node << 6) + lane];   // all 64 slots full
        float m = LEAKY(as[psrc] + adval);
        for (int i = lane; i < no; i += 64) {
            int2 p = ovf[i];
            if (p.x == node) m = fmaxf(m, LEAKY(as[p.y] + adval));
        }
#pragma unroll
        for (int off = 32; off > 0; off >>= 1) m = fmaxf(m, __shfl_xor(m, off, 64));
        float den = 0.f;
        float2 acc = make_float2(0.f, 0.f);
        for (int i = 0; i < 64; i++) {
            int src = csr_pad[(node << 6) + i];
            float e = LEAKY(as[src] + adval);
            float wt = __expf(e - m);
            den += wt;
            float2 v = *(const float2*)(hbase + ((size_t)src << 9) + lane8);
            acc.x += wt * v.x; acc.y += wt * v.y;
        }
        for (int i = 0; i < no; i++) {
            int2 p = ovf[i];
            if (p.x == node) {
                float e = LEAKY(as[p.y] + adval);
                float wt = __expf(e - m);
                den += wt;
                float2 v = *(const float2*)(hbase + ((size_t)p.y << 9) + lane8);
                acc.x += wt * v.x; acc.y += wt * v.y;
            }
        }
        float inv = 1.f / (den + 1e-16f);
        float o0 = acc.x * inv, o1 = acc.y * inv;
        ushort h0 = f32_to_bf16_rne(o0), h1 = f32_to_bf16_rne(o1);
        ((uint2*)aggp)[(size_t)node * 64 + lane] =
            make_uint2((unsigned)h0 | ((unsigned)h1 << 16),
                       pack2(o0 - bf16_to_f32(h0), o1 - bf16_to_f32(h1)));
    }
}

// ---------------- MFMA GEMM + fused epilogue, B staged in LDS ----------------
// 512 threads = 8 waves x 16 rows (128 rows/block). W hi/lo (64 KB) in LDS,
// layout [kchunk][col][8] -> conflict-free b128 reads.
__global__ __launch_bounds__(512) void k_gemm(const uint2* __restrict__ aggp,
        const ushort* __restrict__ wt_hi, const ushort* __restrict__ wt_lo,
        const float* __restrict__ bias, float* __restrict__ hout,
        const float* __restrict__ was_nx, const float* __restrict__ wad_nx,
        float* __restrict__ as_nx, float* __restrict__ ad_nx,
        int n, int do_relu) {
    __shared__ ushort Bh[16 * 128 * 8];   // 32 KB
    __shared__ ushort Bl[16 * 128 * 8];   // 32 KB
    int tid = threadIdx.x;
#pragma unroll
    for (int rep = 0; rep < 4; rep++) {
        int c = rep * 512 + tid;          // 0..2047
        int col = c >> 4, kc = c & 15;
        *(uint4*)(Bh + (size_t)(kc * 128 + col) * 8) = *(const uint4*)(wt_hi + (size_t)col * 128 + kc * 8);
        *(uint4*)(Bl + (size_t)(kc * 128 + col) * 8) = *(const uint4*)(wt_lo + (size_t)col * 128 + kc * 8);
    }
    __syncthreads();

    int wid = tid >> 6, lane = tid & 63;
    int lrow = lane & 15, kgrp = lane >> 4;
    int row_base = blockIdx.x * 128 + wid * 16;

    f32x4 acc[8];
#pragma unroll
    for (int nn = 0; nn < 8; nn++) { acc[nn][0] = 0.f; acc[nn][1] = 0.f; acc[nn][2] = 0.f; acc[nn][3] = 0.f; }

#pragma unroll
    for (int ks = 0; ks < 4; ks++) {
        int kbase = ks * 32 + kgrp * 8;
        int arow = min(row_base + lrow, n - 1);
        const uint2* ap = aggp + (size_t)arow * 64 + (kbase >> 1);
        uint4 q0 = *(const uint4*)ap;
        uint4 q1 = *(const uint4*)(ap + 2);
        int4 hi4 = make_int4(q0.x, q0.z, q1.x, q1.z);
        int4 lo4 = make_int4(q0.y, q0.w, q1.y, q1.w);
        bf16x8 ah = *(bf16x8*)&hi4;
        bf16x8 al = *(bf16x8*)&lo4;
        int kc = ks * 4 + kgrp;
#pragma unroll
        for (int nn = 0; nn < 8; nn++) {
            int col = nn * 16 + lrow;
            bf16x8 bh = *(const bf16x8*)(Bh + (size_t)(kc * 128 + col) * 8);
            bf16x8 bl = *(const bf16x8*)(Bl + (size_t)(kc * 128 + col) * 8);
            acc[nn] = __builtin_amdgcn_mfma_f32_16x16x32_bf16(ah, bh, acc[nn], 0, 0, 0);
            acc[nn] = __builtin_amdgcn_mfma_f32_16x16x32_bf16(ah, bl, acc[nn], 0, 0, 0);
            acc[nn] = __builtin_amdgcn_mfma_f32_16x16x32_bf16(al, bh, acc[nn], 0, 0, 0);
        }
    }

    float bv[8], wsv[8], wdv[8];
#pragma unroll
    for (int nn = 0; nn < 8; nn++) bv[nn] = bias[nn * 16 + lrow];
    if (was_nx) {
#pragma unroll
        for (int nn = 0; nn < 8; nn++) {
            wsv[nn] = was_nx[nn * 16 + lrow];
            wdv[nn] = wad_nx[nn * 16 + lrow];
        }
    }

#pragma unroll
    for (int i = 0; i < 4; i++) {
        int row = row_base + kgrp * 4 + i;
        if (row < n) {
            float ps = 0.f, pd = 0.f;
#pragma unroll
            for (int nn = 0; nn < 8; nn++) {
                float val = acc[nn][i] + bv[nn];
                if (do_relu) val = fmaxf(val, 0.f);
                hout[(size_t)row * 128 + nn * 16 + lrow] = val;
                if (was_nx) { ps += val * wsv[nn]; pd += val * wdv[nn]; }
            }
            if (was_nx) {
#pragma unroll
                for (int off = 1; off < 16; off <<= 1) {
                    ps += __shfl_xor(ps, off, 16);
                    pd += __shfl_xor(pd, off, 16);
                }
                if (lrow == 0) { as_nx[row] = ps; ad_nx[row] = pd; }
            }
        }
    }
}

// ---------------- launch ----------------

extern "C" void kernel_launch(void* const* d_in, const int* in_sizes, int n_in,
                              void* d_out, int out_size, void* d_ws, size_t ws_size,
                              hipStream_t stream) {
    const float* x     = (const float*)d_in[0];
    const int*   ei    = (const int*)d_in[1];
    const float* W_emb = (const float*)d_in[2];
    const float* b_emb = (const float*)d_in[3];
    const float* W1g   = (const float*)d_in[4];
    const float* as1g  = (const float*)d_in[5];
    const float* ad1g  = (const float*)d_in[6];
    const float* b1    = (const float*)d_in[7];
    const float* Wl[3]  = {(const float*)d_in[8],  (const float*)d_in[12], (const float*)d_in[16]};
    const float* asl[3] = {(const float*)d_in[9],  (const float*)d_in[13], (const float*)d_in[17]};
    const float* adl[3] = {(const float*)d_in[10], (const float*)d_in[14], (const float*)d_in[18]};
    const float* bl[3]  = {(const float*)d_in[11], (const float*)d_in[15], (const float*)d_in[19]};
    float* out = (float*)d_out;

    int N = in_sizes[0];
    int E = in_sizes[1] / 2;
    int Et = E + N;
    const int OVF_CAP = 65536;

    char* ws = (char*)d_ws;
    size_t off = 0;
    auto alloc = [&](size_t bytes) { size_t p = off; off += (bytes + 255) & ~(size_t)255; return p; };
    int*   deg      = (int*)(ws + alloc((size_t)N * 4));
    int*   ovf_cnt  = (int*)(ws + alloc(4));
    int2*  ovf      = (int2*)(ws + alloc((size_t)OVF_CAP * 8));
    int*   csr_pad  = (int*)(ws + alloc((size_t)N * 64 * 4));
    float* consts   = (float*)(ws + alloc(272 * 4));
    float* a_s0     = (float*)(ws + alloc((size_t)N * 4));
    float* a_d0     = (float*)(ws + alloc((size_t)N * 4));
    float* a_s1     = (float*)(ws + alloc((size_t)N * 4));
    float* a_d1     = (float*)(ws + alloc((size_t)N * 4));
    float* hA       = (float*)(ws + alloc((size_t)N * 128 * 4));
    unsigned* aggp  = (unsigned*)(ws + alloc((size_t)N * 64 * 8));
    ushort* wt_hi[3]; ushort* wt_lo[3];
    float* was[3]; float* wad[3];
    for (int l = 0; l < 3; l++) {
        wt_hi[l] = (ushort*)(ws + alloc(128 * 128 * 2));
        wt_lo[l] = (ushort*)(ws + alloc(128 * 128 * 2));
        was[l]   = (float*)(ws + alloc(128 * 4));
        wad[l]   = (float*)(ws + alloc(128 * 4));
    }

    hipMemsetAsync(deg, 0, (size_t)N * 4, stream);
    hipMemsetAsync(ovf_cnt, 0, 4, stream);
    k_scatterpad<<<(Et + 255) / 256, 256, 0, stream>>>(ei, E, N, deg, csr_pad,
                                                       ovf_cnt, ovf, OVF_CAP);
    k_prep<<<196, 256, 0, stream>>>(Wl[0], Wl[1], Wl[2], asl[0], asl[1], asl[2],
                                    adl[0], adl[1], adl[2],
                                    W_emb, b_emb, W1g, as1g, ad1g,
                                    wt_hi[0], wt_lo[0], wt_hi[1], wt_lo[1], wt_hi[2], wt_lo[2],
                                    was[0], was[1], was[2], wad[0], wad[1], wad[2],
                                    consts);

    k_l1<<<(N + 63) / 64, 256, 0, stream>>>(x, deg, csr_pad, ovf_cnt, ovf, consts, b1,
                                            was[0], wad[0], hA, a_s0, a_d0, N);

    float* as_cur = a_s0; float* ad_cur = a_d0;
    float* as_nxt = a_s1; float* ad_nxt = a_d1;
    for (int l = 0; l < 3; l++) {
        k_aggh<<<(N + 3) / 4, 256, 0, stream>>>(hA, as_cur, ad_cur, deg, csr_pad,
                                                ovf_cnt, ovf, aggp, N);
        if (l < 2) {
            k_gemm<<<(N + 127) / 128, 512, 0, stream>>>((const uint2*)aggp, wt_hi[l], wt_lo[l], bl[l], hA,
                                                        was[l + 1], wad[l + 1], as_nxt, ad_nxt, N, 1);
            float* t;
            t = as_cur; as_cur = as_nxt; as_nxt = t;
            t = ad_cur; ad_cur = ad_nxt; ad_nxt = t;
        } else {
            k_gemm<<<(N + 127) / 128, 512, 0, stream>>>((const uint2*)aggp, wt_hi[l], wt_lo[l], bl[l], out,
                                                        nullptr, nullptr, nullptr, nullptr, N, 0);
        }
    }
}

// Round 11
// 247.368 us; speedup vs baseline: 1.1781x; 1.0015x over previous
//
#include <hip/hip_runtime.h>
#include <math.h>

// GAT model: N=50000, E=500000 (+N self loops), D=128, layer1 heads=4.
// Structure: k_scatterpad (padded CSR, no scan); k_prep (weights+consts);
// k_l1 (rank-1 layer 1, wave/node); per layer: k_aggh (edge-softmax aggregate
// over h -> bf16 hi/lo panel, roofline-bound) -> k_gemm (MFMA bf16x3, B in LDS,
// A panel preloaded to regs, fused bias/relu/alpha epilogue).

#define LEAKY(e) ((e) > 0.f ? (e) : 0.2f * (e))

typedef __attribute__((ext_vector_type(8))) short bf16x8;
typedef __attribute__((ext_vector_type(4))) float f32x4;

__device__ inline ushort f32_to_bf16_rne(float f) {
    unsigned u = __float_as_uint(f);
    unsigned r = (u + 0x7FFFu + ((u >> 16) & 1u)) >> 16;
    return (ushort)r;
}
__device__ inline float bf16_to_f32(ushort h) { return __uint_as_float((unsigned)h << 16); }
__device__ inline unsigned pack2(float a, float b) {
    return (unsigned)f32_to_bf16_rne(a) | ((unsigned)f32_to_bf16_rne(b) << 16);
}

// ---------------- Padded CSR: one pass, no scan ----------------
// deg has N+1 ints; deg[N] doubles as ovf_cnt (single memset covers both).

__global__ void k_scatterpad(const int* __restrict__ ei, int E, int N,
                             int* __restrict__ deg, int* __restrict__ csr_pad,
                             int2* __restrict__ ovf, int ovf_cap) {
    int e = blockIdx.x * blockDim.x + threadIdx.x;
    int Et = E + N;
    if (e >= Et) return;
    int src, dst;
    if (e < E) { int2 p = ((const int2*)ei)[e]; src = p.x; dst = p.y; }
    else { src = dst = e - E; }
    int pos = atomicAdd(&deg[dst], 1);
    if (pos < 64) {
        csr_pad[(dst << 6) + pos] = src;
    } else {
        int o = atomicAdd(&deg[N], 1);
        if (o < ovf_cap) ovf[o] = make_int2(dst, src);
    }
}

// ---------------- Merged prep: wsplit (blocks 0-191), wvec (192-194), emb (195) ----
// consts layout: u[128]@0, v[128]@128, P[4]@256, Q[4]@260, R[4]@264, S[4]@268

__global__ void k_prep(const float* __restrict__ Wa, const float* __restrict__ Wb,
                       const float* __restrict__ Wc,
                       const float* __restrict__ asa, const float* __restrict__ asb,
                       const float* __restrict__ asc,
                       const float* __restrict__ ada, const float* __restrict__ adb,
                       const float* __restrict__ adc,
                       const float* __restrict__ W_emb, const float* __restrict__ b_emb,
                       const float* __restrict__ W1g, const float* __restrict__ as1g,
                       const float* __restrict__ ad1g,
                       ushort* __restrict__ hi0, ushort* __restrict__ lo0,
                       ushort* __restrict__ hi1, ushort* __restrict__ lo1,
                       ushort* __restrict__ hi2, ushort* __restrict__ lo2,
                       float* __restrict__ was0, float* __restrict__ was1,
                       float* __restrict__ was2,
                       float* __restrict__ wad0, float* __restrict__ wad1,
                       float* __restrict__ wad2,
                       float* __restrict__ consts) {
    __shared__ float su[128], sv[128];
    int b = blockIdx.x, tid = threadIdx.x;
    if (b < 192) {
        int l = b >> 6;
        int idx = (b & 63) * 256 + tid;   // 0..16383
        const float* W = (l == 0) ? Wa : (l == 1) ? Wb : Wc;
        ushort* ph = (l == 0) ? hi0 : (l == 1) ? hi1 : hi2;
        ushort* pl = (l == 0) ? lo0 : (l == 1) ? lo1 : lo2;
        int k = idx >> 7, c = idx & 127;
        float w = W[idx];
        ushort hi = f32_to_bf16_rne(w);
        ushort lo = f32_to_bf16_rne(w - bf16_to_f32(hi));
        ph[c * 128 + k] = hi;     // transposed: [col][k]
        pl[c * 128 + k] = lo;
    } else if (b < 195) {
        if (tid >= 128) return;
        int l = b - 192;
        const float* W  = (l == 0) ? Wa : (l == 1) ? Wb : Wc;
        const float* av = (l == 0) ? asa : (l == 1) ? asb : asc;
        const float* dv = (l == 0) ? ada : (l == 1) ? adb : adc;
        float* ws = (l == 0) ? was0 : (l == 1) ? was1 : was2;
        float* wd = (l == 0) ? wad0 : (l == 1) ? wad1 : wad2;
        int k = tid;
        float s = 0.f, d = 0.f;
        for (int c = 0; c < 128; c++) {
            float w = W[k * 128 + c];
            s += w * av[c];
            d += w * dv[c];
        }
        ws[k] = s; wd[k] = d;
    } else {
        if (tid >= 128) return;
        int f = tid;
        float u = 0.f, v = 0.f;
        for (int k = 0; k < 128; k++) {
            u += W_emb[k] * W1g[k * 128 + f];
            v += b_emb[k] * W1g[k * 128 + f];
        }
        su[f] = u; sv[f] = v;
        consts[f] = u; consts[128 + f] = v;
        __syncthreads();
        if (f < 4) {
            float P = 0.f, Q = 0.f, R = 0.f, S = 0.f;
            for (int j = 0; j < 32; j++) {
                float uu = su[f * 32 + j], vv = sv[f * 32 + j];
                float a = as1g[f * 32 + j], d = ad1g[f * 32 + j];
                P += uu * a; Q += vv * a; R += uu * d; S += vv * d;
            }
            consts[256 + f] = P; consts[260 + f] = Q;
            consts[264 + f] = R; consts[268 + f] = S;
        }
    }
}

// ---------------- Layer 1: one WAVE per node; lane = (edge-lane el, head q) ----
// 16 edge lanes x 4 heads -> edge loop ~1 iteration; reductions: 4 shfl per var.
__global__ __launch_bounds__(256) void k_l1(const float* __restrict__ x,
        const int* __restrict__ deg, const int* __restrict__ csr_pad,
        const int2* __restrict__ ovf,
        const float* __restrict__ consts, const float* __restrict__ b1,
        const float* __restrict__ was2, const float* __restrict__ wad2,
        float* __restrict__ hout, float* __restrict__ a_s, float* __restrict__ a_d,
        int n) {
    int w = threadIdx.x >> 6, lane = threadIdx.x & 63;
    int node = blockIdx.x * 4 + w;
    if (node >= n) return;
    int q = lane & 3;        // head
    int el = lane >> 2;      // edge lane 0..15
    float P = consts[256 + q], Q = consts[260 + q];
    float R = consts[264 + q], Sc = consts[268 + q];
    float xd = x[node];
    float c0 = xd * R + Sc + Q;          // e = leaky(xs*P + c0)
    int dg = deg[node];
    int dlim = min(dg, 64);
    float den = 0.f, S = 0.f;
    for (int i = el; i < dlim; i += 16) {
        float xs = x[csr_pad[(node << 6) + i]];
        float e = xs * P + c0;
        e = LEAKY(e);
        float wgt = __expf(e);
        den += wgt;
        S += wgt * xs;
    }
    if (dg > 64) {
        int no = deg[n];     // ovf count stored at deg[N]
        for (int i = el; i < no; i += 16) {
            int2 p = ovf[i];
            if (p.x == node) {
                float xs = x[p.y];
                float e = xs * P + c0;
                e = LEAKY(e);
                float wgt = __expf(e);
                den += wgt;
                S += wgt * xs;
            }
        }
    }
    // reduce over edge-lanes (same q: lanes differ in bits 2..7)
#pragma unroll
    for (int off = 4; off < 64; off <<= 1) {
        den += __shfl_xor(den, off, 64);
        S += __shfl_xor(S, off, 64);
    }
    float inv = 1.f / (den + 1e-16f);
    float Sn = S * inv, Swn = den * inv;
    // phase 2: lane handles features f, f+1 with f = q*32 + el*2 (head q)
    int f = q * 32 + el * 2;
    float2 u  = *(const float2*)(consts + f);
    float2 v  = *(const float2*)(consts + 128 + f);
    float2 bb = *(const float2*)(b1 + f);
    float2 ws = *(const float2*)(was2 + f);
    float2 wd = *(const float2*)(wad2 + f);
    float v0 = fmaxf(Sn * u.x + Swn * v.x + bb.x, 0.f);
    float v1 = fmaxf(Sn * u.y + Swn * v.y + bb.y, 0.f);
    *(float2*)(hout + (size_t)node * 128 + f) = make_float2(v0, v1);
    float ps = v0 * ws.x + v1 * ws.y;
    float pd = v0 * wd.x + v1 * wd.y;
#pragma unroll
    for (int off = 1; off < 64; off <<= 1) {
        ps += __shfl_xor(ps, off, 64);
        pd += __shfl_xor(pd, off, 64);
    }
    if (lane == 0) { a_s[node] = ps; a_d[node] = pd; }
}

// ---------------- Aggregation over h (f32), output packed bf16 hi/lo ----------------
// One wave per dst node. Fast path: float4 gather, two edges/iteration
// (lanes 0-31 -> edge j, lanes 32-63 -> edge j+1); LDS zero-padded, no tail.
__global__ __launch_bounds__(256) void k_aggh(const float* __restrict__ h,
        const float* __restrict__ as, const float* __restrict__ ad,
        const int* __restrict__ deg, const int* __restrict__ csr_pad,
        const int2* __restrict__ ovf,
        unsigned* __restrict__ aggp, int n) {
    __shared__ int2 s_sw[4][64];
    int w = threadIdx.x >> 6, lane = threadIdx.x & 63;
    int node = blockIdx.x * 4 + w;
    if (node >= n) return;
    int dg = deg[node];
    float adval = ad[node];
    const char* hbase = (const char*)h;

    if (dg <= 64) {
        int boff = 0;
        float e = -INFINITY;
        if (lane < dg) {
            int src = csr_pad[(node << 6) + lane];
            boff = src << 9;                  // src * 512 bytes
            e = LEAKY(as[src] + adval);
        }
        float m = e;
#pragma unroll
        for (int off = 32; off > 0; off >>= 1) m = fmaxf(m, __shfl_xor(m, off, 64));
        float wt = (lane < dg) ? __expf(e - m) : 0.f;
        float den = wt;
#pragma unroll
        for (int off = 32; off > 0; off >>= 1) den += __shfl_xor(den, off, 64);
        s_sw[w][lane] = make_int2(boff, __float_as_int(wt));   // zero-padded beyond deg
        __builtin_amdgcn_wave_barrier();

        int half = lane >> 5;          // which edge of the pair
        int q16 = (lane & 31) * 16;    // byte offset of this lane's feature quad
        float4 acc = make_float4(0.f, 0.f, 0.f, 0.f);
        int degp = (dg + 7) & ~7;
        for (int j = 0; j < degp; j += 8) {
#pragma unroll
            for (int t = 0; t < 4; t++) {
                int2 p = s_sw[w][j + 2 * t + half];
                float4 v = *(const float4*)(hbase + p.x + q16);
                float wt2 = __int_as_float(p.y);
                acc.x += wt2 * v.x; acc.y += wt2 * v.y;
                acc.z += wt2 * v.z; acc.w += wt2 * v.w;
            }
        }
        acc.x += __shfl_xor(acc.x, 32, 64);
        acc.y += __shfl_xor(acc.y, 32, 64);
        acc.z += __shfl_xor(acc.z, 32, 64);
        acc.w += __shfl_xor(acc.w, 32, 64);
        float inv = 1.f / (den + 1e-16f);
        if (lane < 32) {
            float o0 = acc.x * inv, o1 = acc.y * inv;
            float o2 = acc.z * inv, o3 = acc.w * inv;
            ushort h0 = f32_to_bf16_rne(o0), h1 = f32_to_bf16_rne(o1);
            ushort h2 = f32_to_bf16_rne(o2), h3 = f32_to_bf16_rne(o3);
            uint4 pk;
            pk.x = (unsigned)h0 | ((unsigned)h1 << 16);
            pk.y = pack2(o0 - bf16_to_f32(h0), o1 - bf16_to_f32(h1));
            pk.z = (unsigned)h2 | ((unsigned)h3 << 16);
            pk.w = pack2(o2 - bf16_to_f32(h2), o3 - bf16_to_f32(h3));
            ((uint4*)aggp)[(size_t)node * 32 + lane] = pk;
        }
    } else {
        // deg > 64: 64 padded edges + overflow list scan (rare/never on this graph)
        int lane8 = lane * 8;
        int no = deg[n];
        int psrc = csr_pad[(node << 6) + lane];   // all 64 slots full
        float m = LEAKY(as[psrc] + adval);
        for (int i = lane; i < no; i += 64) {
            int2 p = ovf[i];
            if (p.x == node) m = fmaxf(m, LEAKY(as[p.y] + adval));
        }
#pragma unroll
        for (int off = 32; off > 0; off >>= 1) m = fmaxf(m, __shfl_xor(m, off, 64));
        float den = 0.f;
        float2 acc = make_float2(0.f, 0.f);
        for (int i = 0; i < 64; i++) {
            int src = csr_pad[(node << 6) + i];
            float e = LEAKY(as[src] + adval);
            float wt = __expf(e - m);
            den += wt;
            float2 v = *(const float2*)(hbase + ((size_t)src << 9) + lane8);
            acc.x += wt * v.x; acc.y += wt * v.y;
        }
        for (int i = 0; i < no; i++) {
            int2 p = ovf[i];
            if (p.x == node) {
                float e = LEAKY(as[p.y] + adval);
                float wt = __expf(e - m);
                den += wt;
                float2 v = *(const float2*)(hbase + ((size_t)p.y << 9) + lane8);
                acc.x += wt * v.x; acc.y += wt * v.y;
            }
        }
        float inv = 1.f / (den + 1e-16f);
        float o0 = acc.x * inv, o1 = acc.y * inv;
        ushort h0 = f32_to_bf16_rne(o0), h1 = f32_to_bf16_rne(o1);
        ((uint2*)aggp)[(size_t)node * 64 + lane] =
            make_uint2((unsigned)h0 | ((unsigned)h1 << 16),
                       pack2(o0 - bf16_to_f32(h0), o1 - bf16_to_f32(h1)));
    }
}

// ---------------- MFMA GEMM + fused epilogue, B in LDS, A preloaded ----------------
// 512 threads = 8 waves x 16 rows (128 rows/block). W hi/lo (64 KB) in LDS.
// A panel (128 B/lane, all 4 K-steps) preloaded to regs BEFORE the barrier so
// global-load latency overlaps the LDS fill + barrier drain.
__global__ __launch_bounds__(512) void k_gemm(const uint2* __restrict__ aggp,
        const ushort* __restrict__ wt_hi, const ushort* __restrict__ wt_lo,
        const float* __restrict__ bias, float* __restrict__ hout,
        const float* __restrict__ was_nx, const float* __restrict__ wad_nx,
        float* __restrict__ as_nx, float* __restrict__ ad_nx,
        int n, int do_relu) {
    __shared__ ushort Bh[16 * 128 * 8];   // 32 KB
    __shared__ ushort Bl[16 * 128 * 8];   // 32 KB
    int tid = threadIdx.x;
#pragma unroll
    for (int rep = 0; rep < 4; rep++) {
        int c = rep * 512 + tid;          // 0..2047
        int col = c >> 4, kc = c & 15;
        *(uint4*)(Bh + (size_t)(kc * 128 + col) * 8) = *(const uint4*)(wt_hi + (size_t)col * 128 + kc * 8);
        *(uint4*)(Bl + (size_t)(kc * 128 + col) * 8) = *(const uint4*)(wt_lo + (size_t)col * 128 + kc * 8);
    }

    int wid = tid >> 6, lane = tid & 63;
    int lrow = lane & 15, kgrp = lane >> 4;
    int row_base = blockIdx.x * 128 + wid * 16;
    int arow = min(row_base + lrow, n - 1);

    // preload entire A panel for this lane: 8 x uint4 (independent loads)
    const uint4* ap = (const uint4*)(aggp + (size_t)arow * 64);
    uint4 qa[8];
#pragma unroll
    for (int ks = 0; ks < 4; ks++) {
        qa[2 * ks]     = ap[ks * 8 + kgrp * 2];
        qa[2 * ks + 1] = ap[ks * 8 + kgrp * 2 + 1];
    }
    __syncthreads();

    f32x4 acc[8];
#pragma unroll
    for (int nn = 0; nn < 8; nn++) { acc[nn][0] = 0.f; acc[nn][1] = 0.f; acc[nn][2] = 0.f; acc[nn][3] = 0.f; }

#pragma unroll
    for (int ks = 0; ks < 4; ks++) {
        uint4 q0 = qa[2 * ks], q1 = qa[2 * ks + 1];
        int4 hi4 = make_int4(q0.x, q0.z, q1.x, q1.z);
        int4 lo4 = make_int4(q0.y, q0.w, q1.y, q1.w);
        bf16x8 ah = *(bf16x8*)&hi4;
        bf16x8 al = *(bf16x8*)&lo4;
        int kc = ks * 4 + kgrp;
#pragma unroll
        for (int nn = 0; nn < 8; nn++) {
            int col = nn * 16 + lrow;
            bf16x8 bh = *(const bf16x8*)(Bh + (size_t)(kc * 128 + col) * 8);
            bf16x8 bl = *(const bf16x8*)(Bl + (size_t)(kc * 128 + col) * 8);
            acc[nn] = __builtin_amdgcn_mfma_f32_16x16x32_bf16(ah, bh, acc[nn], 0, 0, 0);
            acc[nn] = __builtin_amdgcn_mfma_f32_16x16x32_bf16(ah, bl, acc[nn], 0, 0, 0);
            acc[nn] = __builtin_amdgcn_mfma_f32_16x16x32_bf16(al, bh, acc[nn], 0, 0, 0);
        }
    }

    float bv[8], wsv[8], wdv[8];
#pragma unroll
    for (int nn = 0; nn < 8; nn++) bv[nn] = bias[nn * 16 + lrow];
    if (was_nx) {
#pragma unroll
        for (int nn = 0; nn < 8; nn++) {
            wsv[nn] = was_nx[nn * 16 + lrow];
            wdv[nn] = wad_nx[nn * 16 + lrow];
        }
    }

#pragma unroll
    for (int i = 0; i < 4; i++) {
        int row = row_base + kgrp * 4 + i;
        if (row < n) {
            float ps = 0.f, pd = 0.f;
#pragma unroll
            for (int nn = 0; nn < 8; nn++) {
                float val = acc[nn][i] + bv[nn];
                if (do_relu) val = fmaxf(val, 0.f);
                hout[(size_t)row * 128 + nn * 16 + lrow] = val;
                if (was_nx) { ps += val * wsv[nn]; pd += val * wdv[nn]; }
            }
            if (was_nx) {
#pragma unroll
                for (int off = 1; off < 16; off <<= 1) {
                    ps += __shfl_xor(ps, off, 16);
                    pd += __shfl_xor(pd, off, 16);
                }
                if (lrow == 0) { as_nx[row] = ps; ad_nx[row] = pd; }
            }
        }
    }
}

// ---------------- launch ----------------

extern "C" void kernel_launch(void* const* d_in, const int* in_sizes, int n_in,
                              void* d_out, int out_size, void* d_ws, size_t ws_size,
                              hipStream_t stream) {
    const float* x     = (const float*)d_in[0];
    const int*   ei    = (const int*)d_in[1];
    const float* W_emb = (const float*)d_in[2];
    const float* b_emb = (const float*)d_in[3];
    const float* W1g   = (const float*)d_in[4];
    const float* as1g  = (const float*)d_in[5];
    const float* ad1g  = (const float*)d_in[6];
    const float* b1    = (const float*)d_in[7];
    const float* Wl[3]  = {(const float*)d_in[8],  (const float*)d_in[12], (const float*)d_in[16]};
    const float* asl[3] = {(const float*)d_in[9],  (const float*)d_in[13], (const float*)d_in[17]};
    const float* adl[3] = {(const float*)d_in[10], (const float*)d_in[14], (const float*)d_in[18]};
    const float* bl[3]  = {(const float*)d_in[11], (const float*)d_in[15], (const float*)d_in[19]};
    float* out = (float*)d_out;

    int N = in_sizes[0];
    int E = in_sizes[1] / 2;
    int Et = E + N;
    const int OVF_CAP = 65536;

    char* ws = (char*)d_ws;
    size_t off = 0;
    auto alloc = [&](size_t bytes) { size_t p = off; off += (bytes + 255) & ~(size_t)255; return p; };
    int*   deg      = (int*)(ws + alloc((size_t)(N + 1) * 4));   // deg[N] = ovf count
    int2*  ovf      = (int2*)(ws + alloc((size_t)OVF_CAP * 8));
    int*   csr_pad  = (int*)(ws + alloc((size_t)N * 64 * 4));
    float* consts   = (float*)(ws + alloc(272 * 4));
    float* a_s0     = (float*)(ws + alloc((size_t)N * 4));
    float* a_d0     = (float*)(ws + alloc((size_t)N * 4));
    float* a_s1     = (float*)(ws + alloc((size_t)N * 4));
    float* a_d1     = (float*)(ws + alloc((size_t)N * 4));
    float* hA       = (float*)(ws + alloc((size_t)N * 128 * 4));
    unsigned* aggp  = (unsigned*)(ws + alloc((size_t)N * 64 * 8));
    ushort* wt_hi[3]; ushort* wt_lo[3];
    float* was[3]; float* wad[3];
    for (int l = 0; l < 3; l++) {
        wt_hi[l] = (ushort*)(ws + alloc(128 * 128 * 2));
        wt_lo[l] = (ushort*)(ws + alloc(128 * 128 * 2));
        was[l]   = (float*)(ws + alloc(128 * 4));
        wad[l]   = (float*)(ws + alloc(128 * 4));
    }

    hipMemsetAsync(deg, 0, (size_t)(N + 1) * 4, stream);
    k_scatterpad<<<(Et + 255) / 256, 256, 0, stream>>>(ei, E, N, deg, csr_pad,
                                                       ovf, OVF_CAP);
    k_prep<<<196, 256, 0, stream>>>(Wl[0], Wl[1], Wl[2], asl[0], asl[1], asl[2],
                                    adl[0], adl[1], adl[2],
                                    W_emb, b_emb, W1g, as1g, ad1g,
                                    wt_hi[0], wt_lo[0], wt_hi[1], wt_lo[1], wt_hi[2], wt_lo[2],
                                    was[0], was[1], was[2], wad[0], wad[1], wad[2],
                                    consts);

    k_l1<<<(N + 3) / 4, 256, 0, stream>>>(x, deg, csr_pad, ovf, consts, b1,
                                          was[0], wad[0], hA, a_s0, a_d0, N);

    float* as_cur = a_s0; float* ad_cur = a_d0;
    float* as_nxt = a_s1; float* ad_nxt = a_d1;
    for (int l = 0; l < 3; l++) {
        k_aggh<<<(N + 3) / 4, 256, 0, stream>>>(hA, as_cur, ad_cur, deg, csr_pad,
                                                ovf, aggp, N);
        if (l < 2) {
            k_gemm<<<(N + 127) / 128, 512, 0, stream>>>((const uint2*)aggp, wt_hi[l], wt_lo[l], bl[l], hA,
                                                        was[l + 1], wad[l + 1], as_nxt, ad_nxt, N, 1);
            float* t;
            t = as_cur; as_cur = as_nxt; as_nxt = t;
            t = ad_cur; ad_cur = ad_nxt; ad_nxt = t;
        } else {
            k_gemm<<<(N + 127) / 128, 512, 0, stream>>>((const uint2*)aggp, wt_hi[l], wt_lo[l], bl[l], out,
                                                        nullptr, nullptr, nullptr, nullptr, N, 0);
        }
    }
}